// Round 16
// baseline (430.603 us; speedup 1.0000x reference)
//
#include <hip/hip_runtime.h>
#include <math.h>

#define B_ 4
#define L_ 8192
#define D_ 1024
#define C_ 2048          // L_ / chunk_divisor(=4)
#define CG 128           // chunks per scan group
#define NG (C_/CG)       // 16
#define TAUF 3.0e-4f     // |cos| below this -> exact f32 fixup
#define MAXF 4096
#define FXF 4            // flags per k_fix block

typedef unsigned short ushortt;
using f32x4  = __attribute__((ext_vector_type(4))) float;
using bf16x8 = __attribute__((ext_vector_type(8))) short;

__device__ __forceinline__ ushortt f2bf(float f) {
    unsigned int u = __float_as_uint(f);
    u = (u + 0x7fffu + ((u >> 16) & 1u)) >> 16;   // RNE
    return (ushortt)u;
}
__device__ __forceinline__ float bf2f(ushortt h) {
    return __uint_as_float(((unsigned int)h) << 16);
}

#define GLOAD16(gsrc, ldst) \
    __builtin_amdgcn_global_load_lds( \
        (const __attribute__((address_space(1))) unsigned int*)(gsrc), \
        (__attribute__((address_space(3))) unsigned int*)(ldst), 16, 0, 0)

// 64B-row swizzle (round-11/12 verified: 0 conflicts). Self-inverse.
__device__ __forceinline__ int swz32(int row, int g) { return g ^ ((row >> 1) & 3); }

// ---------------------------------------------------------------------------
// k_prep: E = W - I, rounded to bf16, row-major [e][k]
// ---------------------------------------------------------------------------
__global__ __launch_bounds__(256) void k_prep(
    const float* __restrict__ Wq, const float* __restrict__ Wk,
    ushortt* __restrict__ eqb, ushortt* __restrict__ ekb)
{
    const float* W = blockIdx.y ? Wk : Wq;
    ushortt* E = blockIdx.y ? ekb : eqb;
    size_t i8 = ((size_t)blockIdx.x * 256 + threadIdx.x) * 8;
    int e = (int)(i8 >> 10), k0 = (int)(i8 & 1023);
    float4 a = *(const float4*)&W[i8];
    float4 b = *(const float4*)&W[i8 + 4];
    float v[8] = {a.x, a.y, a.z, a.w, b.x, b.y, b.z, b.w};
    ushortt o[8];
#pragma unroll
    for (int j = 0; j < 8; ++j) {
        float t = v[j] - ((k0 + j == e) ? 1.0f : 0.0f);
        o[j] = f2bf(t);
    }
    *(uint4*)&E[i8] = *(uint4*)o;
}

// ---------------------------------------------------------------------------
// k_xb: x (f32) -> xb (bf16), done once (lives in first half of d_out)
// ---------------------------------------------------------------------------
__global__ __launch_bounds__(256) void k_xb(
    const float* __restrict__ x, ushortt* __restrict__ xb)
{
    size_t i8 = ((size_t)blockIdx.x * 256 + threadIdx.x) * 8;
    float4 a = *(const float4*)&x[i8];
    float4 b = *(const float4*)&x[i8 + 4];
    float v[8] = {a.x, a.y, a.z, a.w, b.x, b.y, b.z, b.w};
    ushortt o[8];
#pragma unroll
    for (int j = 0; j < 8; ++j) o[j] = f2bf(v[j]);
    *(uint4*)&xb[i8] = *(uint4*)o;
}

// ---------------------------------------------------------------------------
// k_gemm (v9): r15 math byte-identical; sync skeleton -> TRIPLE buffer +
// counted vmcnt (T3/T4). Each stage = exactly 3 global_load_lds per thread
// (x=1, E=2; tid<4 extra-row reg load retires in-stage). Per-iter:
//   issue stage(it+2) -> compute buf(it%3) -> s_waitcnt vmcnt(3) -> s_barrier
// vmcnt(3) completes stage(it+1) (older), leaves stage(it+2) in flight —
// prefetch loads now span barriers instead of being drained each iter.
// ---------------------------------------------------------------------------
__global__ __launch_bounds__(512, 4) void k_gemm(
    const ushortt* __restrict__ xb, const ushortt* __restrict__ eqb,
    const ushortt* __restrict__ ekb, float* __restrict__ partsg)
{
    __shared__ ushortt xsh[3][129 * 32];     // 24.2 KB
    __shared__ ushortt eqsh[3][128 * 32];    // 24 KB
    __shared__ ushortt eksh[3][128 * 32];    // 24 KB
    __shared__ float part[128][2][3];        // 3 KB   (total ~75.2 KB)

    const int tid = threadIdx.x;
    const int b = blockIdx.y;
    const int t0 = blockIdx.x * 128;
    const int z = blockIdx.z;                // e-quarter: [z*256, z*256+256)
    const int lane = tid & 63;
    const int w = tid >> 6;
    const int wr = w >> 1;                   // 0..3 : 32-token group
    const int wc = w & 1;                    // 0..1 : 64-ecol group
    const int l15 = lane & 15, lg = lane >> 4;

    const int tq = tid & 255;
    const ushortt* egl = (tid < 256) ? eqb : ekb;

    float nq[8], nk[8], dt[8];
#pragma unroll
    for (int i = 0; i < 8; ++i) { nq[i] = 0.f; nk[i] = 0.f; dt[i] = 0.f; }

    f32x4 aqa[2][4], aka[2][4];
#pragma unroll
    for (int rb = 0; rb < 2; ++rb)
#pragma unroll
        for (int cf = 0; cf < 4; ++cf) {
            aqa[rb][cf] = (f32x4){0.f, 0.f, 0.f, 0.f};
            aka[rb][cf] = (f32x4){0.f, 0.f, 0.f, 0.f};
        }

    auto stage = [&](int it, int buf) {
        const int kb = it & 31, nb = it >> 5;
        const int k0 = kb * 32, e0 = z * 256 + nb * 128;
        uint4 extra;
        if (tid < 4)   // row 128; swz32(128,g)=g -> linear
            extra = *(const uint4*)&xb[((size_t)b * L_ + (t0 + 127)) * D_ + k0 + tid * 8];
        {
            int row = tid >> 2, g = tid & 3;
            int trow = t0 - 1 + row; if (trow < 0) trow = 0;
            const ushortt* src = &xb[((size_t)b * L_ + trow) * D_ + k0 + swz32(row, g) * 8];
            GLOAD16(src, &xsh[buf][tid * 8]);
        }
        ushortt* edst = (tid < 256) ? eqsh[buf] : eksh[buf];
#pragma unroll
        for (int r = 0; r < 2; ++r) {
            int row = r * 64 + (tq >> 2), g = tq & 3;
            const ushortt* src = &egl[(size_t)(e0 + row) * D_ + k0 + swz32(row, g) * 8];
            GLOAD16(src, &edst[r * 2048 + tq * 8]);
        }
        if (tid < 4)
            *(uint4*)&xsh[buf][128 * 32 + tid * 8] = extra;
    };

    // prologue: stage 0 and 1; wait stage0 (oldest 3), keep stage1 in flight
    stage(0, 0);
    stage(1, 1);
    asm volatile("s_waitcnt vmcnt(3) lgkmcnt(0)" ::: "memory");
    __builtin_amdgcn_s_barrier();

    for (int it = 0; it < 64; ++it) {
        const int buf = it % 3;
        if (it + 2 < 64) stage(it + 2, (it + 2) % 3);
        const ushortt* xsb = xsh[buf];
        const ushortt* eqs = eqsh[buf];
        const ushortt* eks = eksh[buf];
        {
            bf16x8 aq[2], ak[2];
#pragma unroll
            for (int rb = 0; rb < 2; ++rb) {
                int rq = 1 + wr * 32 + rb * 16 + l15;
                int rk = rq - 1;
                aq[rb] = *(const bf16x8*)&xsb[rq * 32 + swz32(rq, lg) * 8];
                ak[rb] = *(const bf16x8*)&xsb[rk * 32 + swz32(rk, lg) * 8];
            }
#pragma unroll
            for (int cf = 0; cf < 4; ++cf) {
                int er = wc * 64 + cf * 16 + l15;
                int off = er * 32 + swz32(er, lg) * 8;
                bf16x8 bq = *(const bf16x8*)&eqs[off];
#pragma unroll
                for (int rb = 0; rb < 2; ++rb)
                    aqa[rb][cf] = __builtin_amdgcn_mfma_f32_16x16x32_bf16(aq[rb], bq, aqa[rb][cf], 0, 0, 0);
                bf16x8 bk = *(const bf16x8*)&eks[off];
#pragma unroll
                for (int rb = 0; rb < 2; ++rb)
                    aka[rb][cf] = __builtin_amdgcn_mfma_f32_16x16x32_bf16(ak[rb], bk, aka[rb][cf], 0, 0, 0);
            }
        }
        if ((it & 31) == 31) {
            const int e0 = z * 256 + (it >> 5) * 128;
#pragma unroll
            for (int rb = 0; rb < 2; ++rb)
#pragma unroll
                for (int cf = 0; cf < 4; ++cf) {
                    const int ecol = e0 + wc * 64 + cf * 16 + l15;
                    const int tb = t0 + wr * 32 + rb * 16 + lg * 4;
                    const ushortt* xc = &xb[((size_t)b * L_ + tb) * D_ + ecol];
                    float xt0 = bf2f(xc[0]), xt1 = bf2f(xc[D_]);
                    float xt2 = bf2f(xc[2 * D_]), xt3 = bf2f(xc[3 * D_]);
                    float xm0 = (tb == 0) ? xt0 : bf2f(xc[-(int)D_]);
                    float xtv[4] = {xt0, xt1, xt2, xt3};
                    float xmv[4] = {xm0, xt0, xt1, xt2};
#pragma unroll
                    for (int r = 0; r < 4; ++r) {
                        float qe = xtv[r] + aqa[rb][cf][r];
                        float ke = xmv[r] + aka[rb][cf][r];
                        const int s = rb * 4 + r;
                        nq[s] = fmaf(qe, qe, nq[s]);
                        nk[s] = fmaf(ke, ke, nk[s]);
                        dt[s] = fmaf(qe, ke, dt[s]);
                    }
                }
#pragma unroll
            for (int rb = 0; rb < 2; ++rb)
#pragma unroll
                for (int cf = 0; cf < 4; ++cf) {
                    aqa[rb][cf] = (f32x4){0.f, 0.f, 0.f, 0.f};
                    aka[rb][cf] = (f32x4){0.f, 0.f, 0.f, 0.f};
                }
        }
        // counted wait: stage(it+1) must be complete; stage(it+2) may fly.
        if (it < 62) {
            asm volatile("s_waitcnt vmcnt(3) lgkmcnt(0)" ::: "memory");
        } else {
            asm volatile("s_waitcnt vmcnt(0) lgkmcnt(0)" ::: "memory");
        }
        __builtin_amdgcn_s_barrier();
    }

    // ---- reduce over the 16 ecol-lanes (l15), combine wc halves ----
#pragma unroll
    for (int m = 1; m < 16; m <<= 1) {
#pragma unroll
        for (int s = 0; s < 8; ++s) {
            nq[s] += __shfl_xor(nq[s], m);
            nk[s] += __shfl_xor(nk[s], m);
            dt[s] += __shfl_xor(dt[s], m);
        }
    }
    if (l15 == 0) {
#pragma unroll
        for (int s = 0; s < 8; ++s) {
            int rl = wr * 32 + (s >> 2) * 16 + lg * 4 + (s & 3);
            part[rl][wc][0] = nq[s];
            part[rl][wc][1] = nk[s];
            part[rl][wc][2] = dt[s];
        }
    }
    __syncthreads();
    if (tid < 128) {
        int t = t0 + tid;
        size_t o = ((size_t)(b * L_ + t) * 4 + z) * 3;
        partsg[o + 0] = part[tid][0][0] + part[tid][1][0];
        partsg[o + 1] = part[tid][0][1] + part[tid][1][1];
        partsg[o + 2] = part[tid][0][2] + part[tid][1][2];
    }
}

// ---------------------------------------------------------------------------
// k_pfinal: combine the four e-quarters (float4x3 reads), compute p, flag.
// ---------------------------------------------------------------------------
__global__ __launch_bounds__(256) void k_pfinal(
    const float* __restrict__ partsg, float* __restrict__ p,
    int* __restrict__ cnt, int* __restrict__ flags)
{
    int gid = blockIdx.x * 256 + threadIdx.x;    // b*L + t
    int t = gid & (L_ - 1);
    const float4* pg = (const float4*)&partsg[(size_t)gid * 12];
    float4 v0 = pg[0], v1 = pg[1], v2 = pg[2];
    // layout: [a0 c0 d0 a1][c1 d1 a2 c2][d2 a3 c3 d3]
    float a = v0.x + v0.w + v1.z + v2.y;
    float c = v0.y + v1.x + v1.w + v2.z;
    float d = v0.z + v1.y + v2.x + v2.w;
    float qn = fmaxf(sqrtf(a), 1e-12f);
    float kn = fmaxf(sqrtf(c), 1e-12f);
    float cs = d / (qn * kn);
    float pv = fminf(fmaxf((1.0f - cs) * 0.5f, 0.0f), 1.0f);
    if (t == 0) pv = 1.0f;
    p[gid] = pv;
    if (t > 0 && fabsf(cs) < TAUF) {
        int idx = atomicAdd(cnt, 1);
        if (idx < MAXF) flags[idx] = gid;
    }
}

// ---------------------------------------------------------------------------
// k_fix (v7, r15-proven): FXF=4, 2 blocks/CU.
// ---------------------------------------------------------------------------
__global__ __launch_bounds__(256) void k_fix(
    const float* __restrict__ x, const float* __restrict__ Wq,
    const float* __restrict__ Wk, const int* __restrict__ cnt,
    const int* __restrict__ flags, float* __restrict__ parts)
{
    int n = *cnt; if (n > MAXF) n = MAXF;
    const int m0 = blockIdx.x * FXF;
    if (m0 >= n) return;
    const int e0 = blockIdx.y * 128;

    __shared__ float xs[FXF * 2][1024];   // 32 KB
    __shared__ float ws[2][128 * 17];     // 17 KB
    __shared__ float comb[FXF * 4][128];  // 8 KB
    __shared__ float red2[2][FXF][3];

    const int tid = threadIdx.x;
    const int e = tid & 127;
    const int kh = tid >> 7;

    {
        int row = tid >> 5, c0 = (tid & 31) * 32;
        int f = row >> 1, wh = row & 1;
        int sl = m0 + f;
        int gf = flags[(sl < n) ? sl : m0];
        int fb = gf >> 13, ft = (gf & (L_ - 1)) - wh;
        const float* src = &x[((size_t)fb * L_ + ft) * D_ + c0];
#pragma unroll
        for (int i = 0; i < 8; ++i)
            *(float4*)&xs[row][c0 + i * 4] = *(const float4*)&src[i * 4];
    }

    const int sr = tid >> 1, sk = (tid & 1) * 8;
    const float* gWq = &Wq[(size_t)(e0 + sr) * D_ + sk];
    const float* gWk = &Wk[(size_t)(e0 + sr) * D_ + sk];

    float acc[FXF][2];
#pragma unroll
    for (int f = 0; f < FXF; ++f) { acc[f][0] = 0.f; acc[f][1] = 0.f; }

    float4 pq0 = ((const float4*)gWq)[0], pq1 = ((const float4*)gWq)[1];
    float4 pk0 = ((const float4*)gWk)[0], pk1 = ((const float4*)gWk)[1];

    for (int kc = 0; kc < 64; ++kc) {
        __syncthreads();
        {
            int o = sr * 17 + sk;
            ws[0][o + 0] = pq0.x; ws[0][o + 1] = pq0.y; ws[0][o + 2] = pq0.z; ws[0][o + 3] = pq0.w;
            ws[0][o + 4] = pq1.x; ws[0][o + 5] = pq1.y; ws[0][o + 6] = pq1.z; ws[0][o + 7] = pq1.w;
            ws[1][o + 0] = pk0.x; ws[1][o + 1] = pk0.y; ws[1][o + 2] = pk0.z; ws[1][o + 3] = pk0.w;
            ws[1][o + 4] = pk1.x; ws[1][o + 5] = pk1.y; ws[1][o + 6] = pk1.z; ws[1][o + 7] = pk1.w;
        }
        if (kc + 1 < 64) {
            const float* nq2 = gWq + (kc + 1) * 16;
            const float* nk2 = gWk + (kc + 1) * 16;
            pq0 = ((const float4*)nq2)[0]; pq1 = ((const float4*)nq2)[1];
            pk0 = ((const float4*)nk2)[0]; pk1 = ((const float4*)nk2)[1];
        }
        __syncthreads();
        float wq[8], wk[8];
#pragma unroll
        for (int j = 0; j < 8; ++j) {
            wq[j] = ws[0][e * 17 + kh * 8 + j];
            wk[j] = ws[1][e * 17 + kh * 8 + j];
        }
        const int kbase = kc * 16 + kh * 8;
#pragma unroll
        for (int f = 0; f < FXF; ++f) {
            float aq = acc[f][0], ak = acc[f][1];
#pragma unroll
            for (int j2 = 0; j2 < 2; ++j2) {
                float4 xq = *(const float4*)&xs[f * 2][kbase + j2 * 4];
                float4 xk = *(const float4*)&xs[f * 2 + 1][kbase + j2 * 4];
                aq = fmaf(xq.x, wq[j2 * 4 + 0], aq); aq = fmaf(xq.y, wq[j2 * 4 + 1], aq);
                aq = fmaf(xq.z, wq[j2 * 4 + 2], aq); aq = fmaf(xq.w, wq[j2 * 4 + 3], aq);
                ak = fmaf(xk.x, wk[j2 * 4 + 0], ak); ak = fmaf(xk.y, wk[j2 * 4 + 1], ak);
                ak = fmaf(xk.z, wk[j2 * 4 + 2], ak); ak = fmaf(xk.w, wk[j2 * 4 + 3], ak);
            }
            acc[f][0] = aq; acc[f][1] = ak;
        }
    }

    __syncthreads();
#pragma unroll
    for (int f = 0; f < FXF; ++f) {
        comb[(f * 2 + 0) * 2 + kh][e] = acc[f][0];
        comb[(f * 2 + 1) * 2 + kh][e] = acc[f][1];
    }
    __syncthreads();
    if (tid < 128) {
        float r0[FXF], r1[FXF], r2[FXF];
#pragma unroll
        for (int f = 0; f < FXF; ++f) {
            float q = comb[(f * 2 + 0) * 2 + 0][e] + comb[(f * 2 + 0) * 2 + 1][e];
            float k = comb[(f * 2 + 1) * 2 + 0][e] + comb[(f * 2 + 1) * 2 + 1][e];
            r0[f] = q * q; r1[f] = k * k; r2[f] = q * k;
        }
#pragma unroll
        for (int m = 1; m < 64; m <<= 1) {
#pragma unroll
            for (int f = 0; f < FXF; ++f) {
                r0[f] += __shfl_xor(r0[f], m);
                r1[f] += __shfl_xor(r1[f], m);
                r2[f] += __shfl_xor(r2[f], m);
            }
        }
        if ((tid & 63) == 0) {
            int wv = tid >> 6;
#pragma unroll
            for (int f = 0; f < FXF; ++f) {
                red2[wv][f][0] = r0[f]; red2[wv][f][1] = r1[f]; red2[wv][f][2] = r2[f];
            }
        }
    }
    __syncthreads();
    if (tid < FXF) {
        float A  = red2[0][tid][0] + red2[1][tid][0];
        float Cc = red2[0][tid][1] + red2[1][tid][1];
        float Dd = red2[0][tid][2] + red2[1][tid][2];
        if (m0 + tid < n) {
            size_t o = ((size_t)(m0 + tid) * 8 + blockIdx.y) * 3;
            parts[o] = A; parts[o + 1] = Cc; parts[o + 2] = Dd;
        }
    }
}

__global__ __launch_bounds__(256) void k_fix_final(
    const int* __restrict__ cnt, const int* __restrict__ flags,
    const float* __restrict__ parts, float* __restrict__ p)
{
    int n = *cnt; if (n > MAXF) n = MAXF;
    int f = blockIdx.x * 256 + threadIdx.x;
    if (f >= n) return;
    float a = 0.f, c = 0.f, d = 0.f;
#pragma unroll
    for (int e = 0; e < 8; ++e) {
        size_t o = ((size_t)f * 8 + e) * 3;
        a += parts[o + 0]; c += parts[o + 1]; d += parts[o + 2];
    }
    float qn = fmaxf(sqrtf(a), 1e-12f);
    float kn = fmaxf(sqrtf(c), 1e-12f);
    float cs = d / (qn * kn);
    float pv = fminf(fmaxf((1.0f - cs) * 0.5f, 0.0f), 1.0f);
    p[flags[f]] = pv;
}

// ---------------------------------------------------------------------------
// k_boundaries: compaction + per-chunk coefficient precompute.
// ---------------------------------------------------------------------------
__global__ __launch_bounds__(1024) void k_boundaries(
    const float* __restrict__ p, int* __restrict__ take, int* __restrict__ nch,
    float2* __restrict__ cw, int* __restrict__ segev)
{
    const int b = blockIdx.x;
    const int tid = threadIdx.x;
    __shared__ int ssum[1024];
    __shared__ int tl[C_];

    float4 p0 = *(const float4*)&p[b * L_ + tid * 8];
    float4 p1 = *(const float4*)&p[b * L_ + tid * 8 + 4];
    float pv8[8] = {p0.x, p0.y, p0.z, p0.w, p1.x, p1.y, p1.z, p1.w};
    bool m[8];
    int local = 0;
#pragma unroll
    for (int j = 0; j < 8; ++j) {
        m[j] = (pv8[j] >= 0.5f);
        local += m[j] ? 1 : 0;
    }
    ssum[tid] = local;
    __syncthreads();
    for (int off = 1; off < 1024; off <<= 1) {
        int add = (tid >= off) ? ssum[tid - off] : 0;
        __syncthreads();
        ssum[tid] += add;
        __syncthreads();
    }
    const int total = ssum[1023];
    int rank = ssum[tid] - local;
#pragma unroll
    for (int j = 0; j < 8; ++j) {
        if (m[j]) {
            if (rank < C_) { take[b * C_ + rank] = tid * 8 + j; tl[rank] = tid * 8 + j; }
            ++rank;
        }
    }
    const int K = (total < C_) ? total : C_;
    if (tid == 0) nch[b] = K;
    for (int c = total + tid; c < C_; c += 1024) { take[b * C_ + c] = 0; tl[c] = 0; }
    __syncthreads();
    for (int c = tid; c < C_; c += 1024) {
        int idx = tl[c];
        float pc = p[b * L_ + idx];
        pc = fminf(fmaxf(pc, 1e-4f), 1.f - 1e-4f);
        float dc = (c == 0) ? 0.f : (1.f - pc);
        float wv = (c == 0) ? 1.f : pc;
        cw[b * C_ + c] = make_float2(dc, wv);
        segev[b * C_ + c] = (c + 1 < K) ? tl[c + 1] : L_;
    }
}

// ---------------------------------------------------------------------------
// Scan kernels (unchanged)
// ---------------------------------------------------------------------------
__global__ __launch_bounds__(256) void k_scan_local(
    const float* __restrict__ x, const int* __restrict__ take,
    const float2* __restrict__ cw, float* __restrict__ E, float* __restrict__ M)
{
    const int g = blockIdx.x, b = blockIdx.y, zq = blockIdx.z;
    const int d = zq * 256 + threadIdx.x;
    const int base = b * C_ + g * CG;

    float s = 0.f, mm = 1.f;
    for (int cc = 0; cc < CG; cc += 4) {
        int4 i4 = *(const int4*)&take[base + cc];
        float2 w0 = cw[base + cc], w1 = cw[base + cc + 1];
        float2 w2 = cw[base + cc + 2], w3 = cw[base + cc + 3];
        float x0 = x[((size_t)b * L_ + i4.x) * D_ + d];
        float x1 = x[((size_t)b * L_ + i4.y) * D_ + d];
        float x2 = x[((size_t)b * L_ + i4.z) * D_ + d];
        float x3 = x[((size_t)b * L_ + i4.w) * D_ + d];
        s = fmaf(w0.x, s, w0.y * x0); mm *= w0.x;
        s = fmaf(w1.x, s, w1.y * x1); mm *= w1.x;
        s = fmaf(w2.x, s, w2.y * x2); mm *= w2.x;
        s = fmaf(w3.x, s, w3.y * x3); mm *= w3.x;
    }
    E[((size_t)b * NG + g) * D_ + d] = s;
    if (threadIdx.x == 0 && zq == 0) M[b * NG + g] = mm;
}

__global__ __launch_bounds__(256) void k_scan_groups(
    const float* __restrict__ E, const float* __restrict__ M, float* __restrict__ carry)
{
    const int gid = blockIdx.x * 256 + threadIdx.x;
    const int b = gid >> 10, d = gid & 1023;
    float s = 0.f;
    for (int g = 0; g < NG; ++g) {
        carry[((size_t)b * NG + g) * D_ + d] = s;
        s = E[((size_t)b * NG + g) * D_ + d] + M[b * NG + g] * s;
    }
}

__global__ __launch_bounds__(256) void k_scan_out(
    const float* __restrict__ x, const int* __restrict__ take,
    const float2* __restrict__ cw, const int* __restrict__ segev,
    const int* __restrict__ nch, const float* __restrict__ carry,
    float* __restrict__ last_s, float* __restrict__ out)
{
    const int g = blockIdx.x, b = blockIdx.y, zq = blockIdx.z;
    const int d = zq * 256 + threadIdx.x;
    const int K = nch[b];
    const int c0 = g * CG;
    if (c0 >= K) return;
    const int c1 = (c0 + CG < K) ? (c0 + CG) : K;
    const int base = b * C_;

    float s = carry[((size_t)b * NG + g) * D_ + d];
    int idx = take[base + c0];
    float2 w0 = cw[base + c0];
    float xv = x[((size_t)b * L_ + idx) * D_ + d];
    for (int c = c0; c < c1; ++c) {
        int idxn = 0; float2 wn = make_float2(0.f, 0.f); float xn = 0.f;
        if (c + 1 < c1) {
            idxn = take[base + c + 1];
            wn = cw[base + c + 1];
            xn = x[((size_t)b * L_ + idxn) * D_ + d];
        }
        s = fmaf(w0.x, s, w0.y * xv);
        if (c == K - 1) {
            last_s[b * D_ + d] = s;
        } else {
            int sege = segev[base + c];
            for (int l = idx; l < sege; ++l)
                out[((size_t)b * L_ + l) * D_ + d] = s;
        }
        idx = idxn; w0 = wn; xv = xn;
    }
}

__global__ __launch_bounds__(256) void k_tail(
    const int* __restrict__ take, const int* __restrict__ nch,
    const float* __restrict__ last_s, float* __restrict__ out)
{
    const int b = blockIdx.y;
    const int tt0 = blockIdx.x * 8;
    const int K = nch[b];
    const int start = take[b * C_ + K - 1];
    if (tt0 + 8 <= start) return;
    float4 v = *(const float4*)&last_s[b * D_ + threadIdx.x * 4];
#pragma unroll
    for (int j = 0; j < 8; ++j) {
        int t = tt0 + j;
        if (t >= start)
            *(float4*)&out[((size_t)b * L_ + t) * D_ + threadIdx.x * 4] = v;
    }
}

// ---------------------------------------------------------------------------
extern "C" void kernel_launch(void* const* d_in, const int* in_sizes, int n_in,
                              void* d_out, int out_size, void* d_ws, size_t ws_size,
                              hipStream_t stream)
{
    (void)in_sizes; (void)n_in; (void)out_size;
    const float* x  = (const float*)d_in[0];
    const float* Wq = (const float*)d_in[1];
    const float* Wk = (const float*)d_in[2];
    float* out = (float*)d_out;

    char* ws = (char*)d_ws;
    float*  p      = (float*)(ws + 0);           //  131072
    int*    take   = (int*)  (ws + 131072);      //   32768
    int*    nch    = (int*)  (ws + 163840);      //     256
    float*  M      = (float*)(ws + 164096);      //     512
    float2* cw     = (float2*)(ws + 164608);     //   65536
    int*    segev  = (int*)  (ws + 230144);      //   32768
    float*  last_s = (float*)(ws + 262912);      //   16384
    int*    cnt    = (int*)  (ws + 279296);      //     256
    int*    flags  = (int*)  (ws + 279552);      //   16384
    float*  parts  = (float*)(ws + 295936);      //  393216
    float*  E      = (float*)(ws + 689152);      //  262144
    float*  carry  = (float*)(ws + 951296);      //  262144
    ushortt* eqb   = (ushortt*)(ws + 1213440);   // 2097152
    ushortt* ekb   = (ushortt*)(ws + 3310592);   // 2097152 -> 5407744 total
    if (ws_size < 5407744u) return;

    // Scratch in d_out (128 MB): xb = bf16 x in [0, 64MB);
    // partsg (1.57 MB) at [64MB, ...) — dead before scan_out writes out.
    ushortt* xb = (ushortt*)d_out;
    float* partsg = (float*)((char*)d_out + 67108864);

    hipMemsetAsync(cnt, 0, 256, stream);
    k_prep<<<dim3(512, 2), 256, 0, stream>>>(Wq, Wk, eqb, ekb);
    k_xb<<<16384, 256, 0, stream>>>(x, xb);
    k_gemm<<<dim3(64, B_, 4), 512, 0, stream>>>(xb, eqb, ekb, partsg);
    k_pfinal<<<(B_ * L_) / 256, 256, 0, stream>>>(partsg, p, cnt, flags);
    k_fix<<<dim3(MAXF / FXF, 8), 256, 0, stream>>>(x, Wq, Wk, cnt, flags, parts);
    k_fix_final<<<MAXF / 256, 256, 0, stream>>>(cnt, flags, parts, p);
    k_boundaries<<<B_, 1024, 0, stream>>>(p, take, nch, cw, segev);
    dim3 g3(NG, B_, 4);
    k_scan_local<<<g3, 256, 0, stream>>>(x, take, cw, E, M);
    k_scan_groups<<<(B_ * D_) / 256, 256, 0, stream>>>(E, M, carry);
    k_scan_out<<<g3, 256, 0, stream>>>(x, take, cw, segev, nch, carry, last_s, out);
    k_tail<<<dim3(L_ / 8, B_), 256, 0, stream>>>(take, nch, last_s, out);
}

// Round 17
// 401.756 us; speedup vs baseline: 1.0718x; 1.0718x over previous
//
#include <hip/hip_runtime.h>
#include <math.h>

#define B_ 4
#define L_ 8192
#define D_ 1024
#define C_ 2048          // L_ / chunk_divisor(=4)
#define CG 128           // chunks per scan group
#define NG (C_/CG)       // 16
#define TAUF 3.0e-4f     // |cos| below this -> exact f32 fixup
#define MAXF 4096
#define FXF 4            // flags per k_fix block

typedef unsigned short ushortt;
using f32x4  = __attribute__((ext_vector_type(4))) float;
using bf16x8 = __attribute__((ext_vector_type(8))) short;

__device__ __forceinline__ ushortt f2bf(float f) {
    unsigned int u = __float_as_uint(f);
    u = (u + 0x7fffu + ((u >> 16) & 1u)) >> 16;   // RNE
    return (ushortt)u;
}
__device__ __forceinline__ float bf2f(ushortt h) {
    return __uint_as_float(((unsigned int)h) << 16);
}

#define GLOAD16(gsrc, ldst) \
    __builtin_amdgcn_global_load_lds( \
        (const __attribute__((address_space(1))) unsigned int*)(gsrc), \
        (__attribute__((address_space(3))) unsigned int*)(ldst), 16, 0, 0)

// 64B-row swizzle (round-11/12 verified: 0 conflicts). Self-inverse.
__device__ __forceinline__ int swz32(int row, int g) { return g ^ ((row >> 1) & 3); }

// ---------------------------------------------------------------------------
// k_prep: E = W - I, rounded to bf16, row-major [e][k]
// ---------------------------------------------------------------------------
__global__ __launch_bounds__(256) void k_prep(
    const float* __restrict__ Wq, const float* __restrict__ Wk,
    ushortt* __restrict__ eqb, ushortt* __restrict__ ekb)
{
    const float* W = blockIdx.y ? Wk : Wq;
    ushortt* E = blockIdx.y ? ekb : eqb;
    size_t i8 = ((size_t)blockIdx.x * 256 + threadIdx.x) * 8;
    int e = (int)(i8 >> 10), k0 = (int)(i8 & 1023);
    float4 a = *(const float4*)&W[i8];
    float4 b = *(const float4*)&W[i8 + 4];
    float v[8] = {a.x, a.y, a.z, a.w, b.x, b.y, b.z, b.w};
    ushortt o[8];
#pragma unroll
    for (int j = 0; j < 8; ++j) {
        float t = v[j] - ((k0 + j == e) ? 1.0f : 0.0f);
        o[j] = f2bf(t);
    }
    *(uint4*)&E[i8] = *(uint4*)o;
}

// ---------------------------------------------------------------------------
// k_xb: x (f32) -> xb (bf16), done once (lives in first half of d_out)
// ---------------------------------------------------------------------------
__global__ __launch_bounds__(256) void k_xb(
    const float* __restrict__ x, ushortt* __restrict__ xb)
{
    size_t i8 = ((size_t)blockIdx.x * 256 + threadIdx.x) * 8;
    float4 a = *(const float4*)&x[i8];
    float4 b = *(const float4*)&x[i8 + 4];
    float v[8] = {a.x, a.y, a.z, a.w, b.x, b.y, b.z, b.w};
    ushortt o[8];
#pragma unroll
    for (int j = 0; j < 8; ++j) o[j] = f2bf(v[j]);
    *(uint4*)&xb[i8] = *(uint4*)o;
}

// ---------------------------------------------------------------------------
// k_gemm (r15-proven, byte-identical — FINAL): e-split x4, grid 1024, BK=32,
// swz32 LDS (0 conflicts), x+E double-buffered, one barrier/iter,
// (512,4) -> VGPR 64, no spill. 188 us, MfmaUtil 33%, occ 42%.
// r16 lesson: counted-vmcnt graft onto this 2-phase loop REGRESSES (guide
// §5.5 regime gate) — do not re-attempt without full 8-phase restructure.
// ---------------------------------------------------------------------------
__global__ __launch_bounds__(512, 4) void k_gemm(
    const ushortt* __restrict__ xb, const ushortt* __restrict__ eqb,
    const ushortt* __restrict__ ekb, float* __restrict__ partsg)
{
    __shared__ ushortt xsh[2][129 * 32];     // 16.1 KB
    __shared__ ushortt eqsh[2][128 * 32];    // 16 KB
    __shared__ ushortt eksh[2][128 * 32];    // 16 KB
    __shared__ float part[128][2][3];        // 3 KB

    const int tid = threadIdx.x;
    const int b = blockIdx.y;
    const int t0 = blockIdx.x * 128;
    const int z = blockIdx.z;                // e-quarter: [z*256, z*256+256)
    const int lane = tid & 63;
    const int w = tid >> 6;
    const int wr = w >> 1;                   // 0..3 : 32-token group
    const int wc = w & 1;                    // 0..1 : 64-ecol group
    const int l15 = lane & 15, lg = lane >> 4;

    const int tq = tid & 255;
    const ushortt* egl = (tid < 256) ? eqb : ekb;

    float nq[8], nk[8], dt[8];
#pragma unroll
    for (int i = 0; i < 8; ++i) { nq[i] = 0.f; nk[i] = 0.f; dt[i] = 0.f; }

    f32x4 aqa[2][4], aka[2][4];
#pragma unroll
    for (int rb = 0; rb < 2; ++rb)
#pragma unroll
        for (int cf = 0; cf < 4; ++cf) {
            aqa[rb][cf] = (f32x4){0.f, 0.f, 0.f, 0.f};
            aka[rb][cf] = (f32x4){0.f, 0.f, 0.f, 0.f};
        }

    auto stage = [&](int it, int buf) {
        const int kb = it & 31, nb = it >> 5;
        const int k0 = kb * 32, e0 = z * 256 + nb * 128;
        uint4 extra;
        if (tid < 4)   // row 128; swz32(128,g)=g -> linear
            extra = *(const uint4*)&xb[((size_t)b * L_ + (t0 + 127)) * D_ + k0 + tid * 8];
        {
            int row = tid >> 2, g = tid & 3;
            int trow = t0 - 1 + row; if (trow < 0) trow = 0;
            const ushortt* src = &xb[((size_t)b * L_ + trow) * D_ + k0 + swz32(row, g) * 8];
            GLOAD16(src, &xsh[buf][tid * 8]);
        }
        ushortt* edst = (tid < 256) ? eqsh[buf] : eksh[buf];
#pragma unroll
        for (int r = 0; r < 2; ++r) {
            int row = r * 64 + (tq >> 2), g = tq & 3;
            const ushortt* src = &egl[(size_t)(e0 + row) * D_ + k0 + swz32(row, g) * 8];
            GLOAD16(src, &edst[r * 2048 + tq * 8]);
        }
        if (tid < 4)
            *(uint4*)&xsh[buf][128 * 32 + tid * 8] = extra;
    };

    stage(0, 0);
    __syncthreads();

    int buf = 0;
    for (int it = 0; it < 64; ++it) {
        if (it + 1 < 64) stage(it + 1, buf ^ 1);
        const ushortt* xsb = xsh[buf];
        const ushortt* eqs = eqsh[buf];
        const ushortt* eks = eksh[buf];
        {
            bf16x8 aq[2], ak[2];
#pragma unroll
            for (int rb = 0; rb < 2; ++rb) {
                int rq = 1 + wr * 32 + rb * 16 + l15;
                int rk = rq - 1;
                aq[rb] = *(const bf16x8*)&xsb[rq * 32 + swz32(rq, lg) * 8];
                ak[rb] = *(const bf16x8*)&xsb[rk * 32 + swz32(rk, lg) * 8];
            }
#pragma unroll
            for (int cf = 0; cf < 4; ++cf) {
                int er = wc * 64 + cf * 16 + l15;
                int off = er * 32 + swz32(er, lg) * 8;
                bf16x8 bq = *(const bf16x8*)&eqs[off];
#pragma unroll
                for (int rb = 0; rb < 2; ++rb)
                    aqa[rb][cf] = __builtin_amdgcn_mfma_f32_16x16x32_bf16(aq[rb], bq, aqa[rb][cf], 0, 0, 0);
                bf16x8 bk = *(const bf16x8*)&eks[off];
#pragma unroll
                for (int rb = 0; rb < 2; ++rb)
                    aka[rb][cf] = __builtin_amdgcn_mfma_f32_16x16x32_bf16(ak[rb], bk, aka[rb][cf], 0, 0, 0);
            }
        }
        if ((it & 31) == 31) {
            const int e0 = z * 256 + (it >> 5) * 128;
#pragma unroll
            for (int rb = 0; rb < 2; ++rb)
#pragma unroll
                for (int cf = 0; cf < 4; ++cf) {
                    const int ecol = e0 + wc * 64 + cf * 16 + l15;
                    const int tb = t0 + wr * 32 + rb * 16 + lg * 4;
                    const ushortt* xc = &xb[((size_t)b * L_ + tb) * D_ + ecol];
                    float xt0 = bf2f(xc[0]), xt1 = bf2f(xc[D_]);
                    float xt2 = bf2f(xc[2 * D_]), xt3 = bf2f(xc[3 * D_]);
                    float xm0 = (tb == 0) ? xt0 : bf2f(xc[-(int)D_]);
                    float xtv[4] = {xt0, xt1, xt2, xt3};
                    float xmv[4] = {xm0, xt0, xt1, xt2};
#pragma unroll
                    for (int r = 0; r < 4; ++r) {
                        float qe = xtv[r] + aqa[rb][cf][r];
                        float ke = xmv[r] + aka[rb][cf][r];
                        const int s = rb * 4 + r;
                        nq[s] = fmaf(qe, qe, nq[s]);
                        nk[s] = fmaf(ke, ke, nk[s]);
                        dt[s] = fmaf(qe, ke, dt[s]);
                    }
                }
#pragma unroll
            for (int rb = 0; rb < 2; ++rb)
#pragma unroll
                for (int cf = 0; cf < 4; ++cf) {
                    aqa[rb][cf] = (f32x4){0.f, 0.f, 0.f, 0.f};
                    aka[rb][cf] = (f32x4){0.f, 0.f, 0.f, 0.f};
                }
        }
        __syncthreads();
        buf ^= 1;
    }

#pragma unroll
    for (int m = 1; m < 16; m <<= 1) {
#pragma unroll
        for (int s = 0; s < 8; ++s) {
            nq[s] += __shfl_xor(nq[s], m);
            nk[s] += __shfl_xor(nk[s], m);
            dt[s] += __shfl_xor(dt[s], m);
        }
    }
    if (l15 == 0) {
#pragma unroll
        for (int s = 0; s < 8; ++s) {
            int rl = wr * 32 + (s >> 2) * 16 + lg * 4 + (s & 3);
            part[rl][wc][0] = nq[s];
            part[rl][wc][1] = nk[s];
            part[rl][wc][2] = dt[s];
        }
    }
    __syncthreads();
    if (tid < 128) {
        int t = t0 + tid;
        size_t o = ((size_t)(b * L_ + t) * 4 + z) * 3;
        partsg[o + 0] = part[tid][0][0] + part[tid][1][0];
        partsg[o + 1] = part[tid][0][1] + part[tid][1][1];
        partsg[o + 2] = part[tid][0][2] + part[tid][1][2];
    }
}

// ---------------------------------------------------------------------------
// k_pfinal: combine the four e-quarters (float4x3 reads), compute p, flag.
// ---------------------------------------------------------------------------
__global__ __launch_bounds__(256) void k_pfinal(
    const float* __restrict__ partsg, float* __restrict__ p,
    int* __restrict__ cnt, int* __restrict__ flags)
{
    int gid = blockIdx.x * 256 + threadIdx.x;    // b*L + t
    int t = gid & (L_ - 1);
    const float4* pg = (const float4*)&partsg[(size_t)gid * 12];
    float4 v0 = pg[0], v1 = pg[1], v2 = pg[2];
    // layout: [a0 c0 d0 a1][c1 d1 a2 c2][d2 a3 c3 d3]
    float a = v0.x + v0.w + v1.z + v2.y;
    float c = v0.y + v1.x + v1.w + v2.z;
    float d = v0.z + v1.y + v2.x + v2.w;
    float qn = fmaxf(sqrtf(a), 1e-12f);
    float kn = fmaxf(sqrtf(c), 1e-12f);
    float cs = d / (qn * kn);
    float pv = fminf(fmaxf((1.0f - cs) * 0.5f, 0.0f), 1.0f);
    if (t == 0) pv = 1.0f;
    p[gid] = pv;
    if (t > 0 && fabsf(cs) < TAUF) {
        int idx = atomicAdd(cnt, 1);
        if (idx < MAXF) flags[idx] = gid;
    }
}

// ---------------------------------------------------------------------------
// k_fix (v7, r15-proven): FXF=4, 2 blocks/CU.
// ---------------------------------------------------------------------------
__global__ __launch_bounds__(256) void k_fix(
    const float* __restrict__ x, const float* __restrict__ Wq,
    const float* __restrict__ Wk, const int* __restrict__ cnt,
    const int* __restrict__ flags, float* __restrict__ parts)
{
    int n = *cnt; if (n > MAXF) n = MAXF;
    const int m0 = blockIdx.x * FXF;
    if (m0 >= n) return;
    const int e0 = blockIdx.y * 128;

    __shared__ float xs[FXF * 2][1024];   // 32 KB
    __shared__ float ws[2][128 * 17];     // 17 KB
    __shared__ float comb[FXF * 4][128];  // 8 KB
    __shared__ float red2[2][FXF][3];

    const int tid = threadIdx.x;
    const int e = tid & 127;
    const int kh = tid >> 7;

    {
        int row = tid >> 5, c0 = (tid & 31) * 32;
        int f = row >> 1, wh = row & 1;
        int sl = m0 + f;
        int gf = flags[(sl < n) ? sl : m0];
        int fb = gf >> 13, ft = (gf & (L_ - 1)) - wh;
        const float* src = &x[((size_t)fb * L_ + ft) * D_ + c0];
#pragma unroll
        for (int i = 0; i < 8; ++i)
            *(float4*)&xs[row][c0 + i * 4] = *(const float4*)&src[i * 4];
    }

    const int sr = tid >> 1, sk = (tid & 1) * 8;
    const float* gWq = &Wq[(size_t)(e0 + sr) * D_ + sk];
    const float* gWk = &Wk[(size_t)(e0 + sr) * D_ + sk];

    float acc[FXF][2];
#pragma unroll
    for (int f = 0; f < FXF; ++f) { acc[f][0] = 0.f; acc[f][1] = 0.f; }

    float4 pq0 = ((const float4*)gWq)[0], pq1 = ((const float4*)gWq)[1];
    float4 pk0 = ((const float4*)gWk)[0], pk1 = ((const float4*)gWk)[1];

    for (int kc = 0; kc < 64; ++kc) {
        __syncthreads();
        {
            int o = sr * 17 + sk;
            ws[0][o + 0] = pq0.x; ws[0][o + 1] = pq0.y; ws[0][o + 2] = pq0.z; ws[0][o + 3] = pq0.w;
            ws[0][o + 4] = pq1.x; ws[0][o + 5] = pq1.y; ws[0][o + 6] = pq1.z; ws[0][o + 7] = pq1.w;
            ws[1][o + 0] = pk0.x; ws[1][o + 1] = pk0.y; ws[1][o + 2] = pk0.z; ws[1][o + 3] = pk0.w;
            ws[1][o + 4] = pk1.x; ws[1][o + 5] = pk1.y; ws[1][o + 6] = pk1.z; ws[1][o + 7] = pk1.w;
        }
        if (kc + 1 < 64) {
            const float* nq2 = gWq + (kc + 1) * 16;
            const float* nk2 = gWk + (kc + 1) * 16;
            pq0 = ((const float4*)nq2)[0]; pq1 = ((const float4*)nq2)[1];
            pk0 = ((const float4*)nk2)[0]; pk1 = ((const float4*)nk2)[1];
        }
        __syncthreads();
        float wq[8], wk[8];
#pragma unroll
        for (int j = 0; j < 8; ++j) {
            wq[j] = ws[0][e * 17 + kh * 8 + j];
            wk[j] = ws[1][e * 17 + kh * 8 + j];
        }
        const int kbase = kc * 16 + kh * 8;
#pragma unroll
        for (int f = 0; f < FXF; ++f) {
            float aq = acc[f][0], ak = acc[f][1];
#pragma unroll
            for (int j2 = 0; j2 < 2; ++j2) {
                float4 xq = *(const float4*)&xs[f * 2][kbase + j2 * 4];
                float4 xk = *(const float4*)&xs[f * 2 + 1][kbase + j2 * 4];
                aq = fmaf(xq.x, wq[j2 * 4 + 0], aq); aq = fmaf(xq.y, wq[j2 * 4 + 1], aq);
                aq = fmaf(xq.z, wq[j2 * 4 + 2], aq); aq = fmaf(xq.w, wq[j2 * 4 + 3], aq);
                ak = fmaf(xk.x, wk[j2 * 4 + 0], ak); ak = fmaf(xk.y, wk[j2 * 4 + 1], ak);
                ak = fmaf(xk.z, wk[j2 * 4 + 2], ak); ak = fmaf(xk.w, wk[j2 * 4 + 3], ak);
            }
            acc[f][0] = aq; acc[f][1] = ak;
        }
    }

    __syncthreads();
#pragma unroll
    for (int f = 0; f < FXF; ++f) {
        comb[(f * 2 + 0) * 2 + kh][e] = acc[f][0];
        comb[(f * 2 + 1) * 2 + kh][e] = acc[f][1];
    }
    __syncthreads();
    if (tid < 128) {
        float r0[FXF], r1[FXF], r2[FXF];
#pragma unroll
        for (int f = 0; f < FXF; ++f) {
            float q = comb[(f * 2 + 0) * 2 + 0][e] + comb[(f * 2 + 0) * 2 + 1][e];
            float k = comb[(f * 2 + 1) * 2 + 0][e] + comb[(f * 2 + 1) * 2 + 1][e];
            r0[f] = q * q; r1[f] = k * k; r2[f] = q * k;
        }
#pragma unroll
        for (int m = 1; m < 64; m <<= 1) {
#pragma unroll
            for (int f = 0; f < FXF; ++f) {
                r0[f] += __shfl_xor(r0[f], m);
                r1[f] += __shfl_xor(r1[f], m);
                r2[f] += __shfl_xor(r2[f], m);
            }
        }
        if ((tid & 63) == 0) {
            int wv = tid >> 6;
#pragma unroll
            for (int f = 0; f < FXF; ++f) {
                red2[wv][f][0] = r0[f]; red2[wv][f][1] = r1[f]; red2[wv][f][2] = r2[f];
            }
        }
    }
    __syncthreads();
    if (tid < FXF) {
        float A  = red2[0][tid][0] + red2[1][tid][0];
        float Cc = red2[0][tid][1] + red2[1][tid][1];
        float Dd = red2[0][tid][2] + red2[1][tid][2];
        if (m0 + tid < n) {
            size_t o = ((size_t)(m0 + tid) * 8 + blockIdx.y) * 3;
            parts[o] = A; parts[o + 1] = Cc; parts[o + 2] = Dd;
        }
    }
}

__global__ __launch_bounds__(256) void k_fix_final(
    const int* __restrict__ cnt, const int* __restrict__ flags,
    const float* __restrict__ parts, float* __restrict__ p)
{
    int n = *cnt; if (n > MAXF) n = MAXF;
    int f = blockIdx.x * 256 + threadIdx.x;
    if (f >= n) return;
    float a = 0.f, c = 0.f, d = 0.f;
#pragma unroll
    for (int e = 0; e < 8; ++e) {
        size_t o = ((size_t)f * 8 + e) * 3;
        a += parts[o + 0]; c += parts[o + 1]; d += parts[o + 2];
    }
    float qn = fmaxf(sqrtf(a), 1e-12f);
    float kn = fmaxf(sqrtf(c), 1e-12f);
    float cs = d / (qn * kn);
    float pv = fminf(fmaxf((1.0f - cs) * 0.5f, 0.0f), 1.0f);
    p[flags[f]] = pv;
}

// ---------------------------------------------------------------------------
// k_boundaries: compaction + per-chunk coefficient precompute.
// ---------------------------------------------------------------------------
__global__ __launch_bounds__(1024) void k_boundaries(
    const float* __restrict__ p, int* __restrict__ take, int* __restrict__ nch,
    float2* __restrict__ cw, int* __restrict__ segev)
{
    const int b = blockIdx.x;
    const int tid = threadIdx.x;
    __shared__ int ssum[1024];
    __shared__ int tl[C_];

    float4 p0 = *(const float4*)&p[b * L_ + tid * 8];
    float4 p1 = *(const float4*)&p[b * L_ + tid * 8 + 4];
    float pv8[8] = {p0.x, p0.y, p0.z, p0.w, p1.x, p1.y, p1.z, p1.w};
    bool m[8];
    int local = 0;
#pragma unroll
    for (int j = 0; j < 8; ++j) {
        m[j] = (pv8[j] >= 0.5f);
        local += m[j] ? 1 : 0;
    }
    ssum[tid] = local;
    __syncthreads();
    for (int off = 1; off < 1024; off <<= 1) {
        int add = (tid >= off) ? ssum[tid - off] : 0;
        __syncthreads();
        ssum[tid] += add;
        __syncthreads();
    }
    const int total = ssum[1023];
    int rank = ssum[tid] - local;
#pragma unroll
    for (int j = 0; j < 8; ++j) {
        if (m[j]) {
            if (rank < C_) { take[b * C_ + rank] = tid * 8 + j; tl[rank] = tid * 8 + j; }
            ++rank;
        }
    }
    const int K = (total < C_) ? total : C_;
    if (tid == 0) nch[b] = K;
    for (int c = total + tid; c < C_; c += 1024) { take[b * C_ + c] = 0; tl[c] = 0; }
    __syncthreads();
    for (int c = tid; c < C_; c += 1024) {
        int idx = tl[c];
        float pc = p[b * L_ + idx];
        pc = fminf(fmaxf(pc, 1e-4f), 1.f - 1e-4f);
        float dc = (c == 0) ? 0.f : (1.f - pc);
        float wv = (c == 0) ? 1.f : pc;
        cw[b * C_ + c] = make_float2(dc, wv);
        segev[b * C_ + c] = (c + 1 < K) ? tl[c + 1] : L_;
    }
}

// ---------------------------------------------------------------------------
// Scan kernels (unchanged)
// ---------------------------------------------------------------------------
__global__ __launch_bounds__(256) void k_scan_local(
    const float* __restrict__ x, const int* __restrict__ take,
    const float2* __restrict__ cw, float* __restrict__ E, float* __restrict__ M)
{
    const int g = blockIdx.x, b = blockIdx.y, zq = blockIdx.z;
    const int d = zq * 256 + threadIdx.x;
    const int base = b * C_ + g * CG;

    float s = 0.f, mm = 1.f;
    for (int cc = 0; cc < CG; cc += 4) {
        int4 i4 = *(const int4*)&take[base + cc];
        float2 w0 = cw[base + cc], w1 = cw[base + cc + 1];
        float2 w2 = cw[base + cc + 2], w3 = cw[base + cc + 3];
        float x0 = x[((size_t)b * L_ + i4.x) * D_ + d];
        float x1 = x[((size_t)b * L_ + i4.y) * D_ + d];
        float x2 = x[((size_t)b * L_ + i4.z) * D_ + d];
        float x3 = x[((size_t)b * L_ + i4.w) * D_ + d];
        s = fmaf(w0.x, s, w0.y * x0); mm *= w0.x;
        s = fmaf(w1.x, s, w1.y * x1); mm *= w1.x;
        s = fmaf(w2.x, s, w2.y * x2); mm *= w2.x;
        s = fmaf(w3.x, s, w3.y * x3); mm *= w3.x;
    }
    E[((size_t)b * NG + g) * D_ + d] = s;
    if (threadIdx.x == 0 && zq == 0) M[b * NG + g] = mm;
}

__global__ __launch_bounds__(256) void k_scan_groups(
    const float* __restrict__ E, const float* __restrict__ M, float* __restrict__ carry)
{
    const int gid = blockIdx.x * 256 + threadIdx.x;
    const int b = gid >> 10, d = gid & 1023;
    float s = 0.f;
    for (int g = 0; g < NG; ++g) {
        carry[((size_t)b * NG + g) * D_ + d] = s;
        s = E[((size_t)b * NG + g) * D_ + d] + M[b * NG + g] * s;
    }
}

__global__ __launch_bounds__(256) void k_scan_out(
    const float* __restrict__ x, const int* __restrict__ take,
    const float2* __restrict__ cw, const int* __restrict__ segev,
    const int* __restrict__ nch, const float* __restrict__ carry,
    float* __restrict__ last_s, float* __restrict__ out)
{
    const int g = blockIdx.x, b = blockIdx.y, zq = blockIdx.z;
    const int d = zq * 256 + threadIdx.x;
    const int K = nch[b];
    const int c0 = g * CG;
    if (c0 >= K) return;
    const int c1 = (c0 + CG < K) ? (c0 + CG) : K;
    const int base = b * C_;

    float s = carry[((size_t)b * NG + g) * D_ + d];
    int idx = take[base + c0];
    float2 w0 = cw[base + c0];
    float xv = x[((size_t)b * L_ + idx) * D_ + d];
    for (int c = c0; c < c1; ++c) {
        int idxn = 0; float2 wn = make_float2(0.f, 0.f); float xn = 0.f;
        if (c + 1 < c1) {
            idxn = take[base + c + 1];
            wn = cw[base + c + 1];
            xn = x[((size_t)b * L_ + idxn) * D_ + d];
        }
        s = fmaf(w0.x, s, w0.y * xv);
        if (c == K - 1) {
            last_s[b * D_ + d] = s;
        } else {
            int sege = segev[base + c];
            for (int l = idx; l < sege; ++l)
                out[((size_t)b * L_ + l) * D_ + d] = s;
        }
        idx = idxn; w0 = wn; xv = xn;
    }
}

__global__ __launch_bounds__(256) void k_tail(
    const int* __restrict__ take, const int* __restrict__ nch,
    const float* __restrict__ last_s, float* __restrict__ out)
{
    const int b = blockIdx.y;
    const int tt0 = blockIdx.x * 8;
    const int K = nch[b];
    const int start = take[b * C_ + K - 1];
    if (tt0 + 8 <= start) return;
    float4 v = *(const float4*)&last_s[b * D_ + threadIdx.x * 4];
#pragma unroll
    for (int j = 0; j < 8; ++j) {
        int t = tt0 + j;
        if (t >= start)
            *(float4*)&out[((size_t)b * L_ + t) * D_ + threadIdx.x * 4] = v;
    }
}

// ---------------------------------------------------------------------------
extern "C" void kernel_launch(void* const* d_in, const int* in_sizes, int n_in,
                              void* d_out, int out_size, void* d_ws, size_t ws_size,
                              hipStream_t stream)
{
    (void)in_sizes; (void)n_in; (void)out_size;
    const float* x  = (const float*)d_in[0];
    const float* Wq = (const float*)d_in[1];
    const float* Wk = (const float*)d_in[2];
    float* out = (float*)d_out;

    char* ws = (char*)d_ws;
    float*  p      = (float*)(ws + 0);           //  131072
    int*    take   = (int*)  (ws + 131072);      //   32768
    int*    nch    = (int*)  (ws + 163840);      //     256
    float*  M      = (float*)(ws + 164096);      //     512
    float2* cw     = (float2*)(ws + 164608);     //   65536
    int*    segev  = (int*)  (ws + 230144);      //   32768
    float*  last_s = (float*)(ws + 262912);      //   16384
    int*    cnt    = (int*)  (ws + 279296);      //     256
    int*    flags  = (int*)  (ws + 279552);      //   16384
    float*  parts  = (float*)(ws + 295936);      //  393216
    float*  E      = (float*)(ws + 689152);      //  262144
    float*  carry  = (float*)(ws + 951296);      //  262144
    ushortt* eqb   = (ushortt*)(ws + 1213440);   // 2097152
    ushortt* ekb   = (ushortt*)(ws + 3310592);   // 2097152 -> 5407744 total
    if (ws_size < 5407744u) return;

    // Scratch in d_out (128 MB): xb = bf16 x in [0, 64MB);
    // partsg (1.57 MB) at [64MB, ...) — dead before scan_out writes out.
    ushortt* xb = (ushortt*)d_out;
    float* partsg = (float*)((char*)d_out + 67108864);

    hipMemsetAsync(cnt, 0, 256, stream);
    k_prep<<<dim3(512, 2), 256, 0, stream>>>(Wq, Wk, eqb, ekb);
    k_xb<<<16384, 256, 0, stream>>>(x, xb);
    k_gemm<<<dim3(64, B_, 4), 512, 0, stream>>>(xb, eqb, ekb, partsg);
    k_pfinal<<<(B_ * L_) / 256, 256, 0, stream>>>(partsg, p, cnt, flags);
    k_fix<<<dim3(MAXF / FXF, 8), 256, 0, stream>>>(x, Wq, Wk, cnt, flags, parts);
    k_fix_final<<<MAXF / 256, 256, 0, stream>>>(cnt, flags, parts, p);
    k_boundaries<<<B_, 1024, 0, stream>>>(p, take, nch, cw, segev);
    dim3 g3(NG, B_, 4);
    k_scan_local<<<g3, 256, 0, stream>>>(x, take, cw, E, M);
    k_scan_groups<<<(B_ * D_) / 256, 256, 0, stream>>>(E, M, carry);
    k_scan_out<<<g3, 256, 0, stream>>>(x, take, cw, segev, nch, carry, last_s, out);
    k_tail<<<dim3(L_ / 8, B_), 256, 0, stream>>>(take, nch, last_s, out);
}